// Round 1
// baseline (125.754 us; speedup 1.0000x reference)
//
#include <hip/hip_runtime.h>
#include <stdint.h>

typedef __bf16 bf16x8 __attribute__((ext_vector_type(8)));
typedef float f32x4 __attribute__((ext_vector_type(4)));
typedef __attribute__((address_space(3))) uint32_t as3u32;
typedef const __attribute__((address_space(1))) uint32_t as1u32;

#define B_TOT 8192
#define DD 128
#define OUT_TOT 67108864UL
#define OUT_AVG 67117056UL

__device__ inline unsigned short f2bf(float x){
  union { float f; uint32_t u; } v; v.f = x;
  return (unsigned short)((v.u + 0x7fffu + ((v.u >> 16) & 1u)) >> 16);
}

// ---------------- phase 0: W1 -> bf16 ----------------
__global__ __launch_bounds__(256) void k_convw(const float* __restrict__ W1,
                                               unsigned short* __restrict__ W1b){
  int i = blockIdx.x * 256 + threadIdx.x;   // grid 64 -> 16384
  W1b[i] = f2bf(W1[i]);
}

// ---------------- phase 1: gather + normalize + h + pos ----------------
__device__ inline float bsum128(float v, volatile float* s2){
  #pragma unroll
  for (int o = 32; o; o >>= 1) v += __shfl_xor(v, o);
  __syncthreads();
  if ((threadIdx.x & 63) == 0) s2[threadIdx.x >> 6] = v;
  __syncthreads();
  return s2[0] + s2[1];
}

__global__ __launch_bounds__(128) void k_feat(const float* __restrict__ x1,
    const float* __restrict__ x2, const int* __restrict__ i1a, const int* __restrict__ i2a,
    unsigned short* __restrict__ f1b, unsigned short* __restrict__ f2b,
    unsigned short* __restrict__ hb, float* __restrict__ posw){
  __shared__ float s2[2];
  int b = blockIdx.x, t = threadIdx.x;
  size_t r1 = (size_t)i1a[b] * DD, r2 = (size_t)i2a[b] * DD;
  float v1 = x1[r1 + t], v2 = x2[r2 + t];
  float n1 = sqrtf(bsum128(v1 * v1, s2));
  float f1 = v1 / fmaxf(n1, 1e-12f);
  float n2 = sqrtf(bsum128(v2 * v2, s2));
  float f2 = v2 / fmaxf(n2, 1e-12f);
  float h = f1 * f2;
  float pos = bsum128(h, s2);
  int o = b * DD + t;
  f1b[o] = f2bf(f1); f2b[o] = f2bf(f2); hb[o] = f2bf(h);
  if (t == 0) posw[b] = pos;
}

// ---------------- shared GEMM tile machinery (128x128, K=128, NT) ----------------
// LDS layout: row-major [128][128] bf16 with 16B-chunk XOR swizzle:
// LDS chunk (row, cc) holds global chunk (row, cc ^ (row&7)).
// global_load_lds writes LDS linearly (wave-uniform base + lane*16) so we
// pre-swizzle the per-lane GLOBAL source address (rule #21: both sides or neither).
__device__ inline void stage_tile(const unsigned short* g, unsigned short* s){
  int tid = threadIdx.x;
  #pragma unroll
  for (int it = 0; it < 8; ++it){
    int c = tid + it * 256;          // 2048 chunks of 16B
    int row = c >> 4, cc = c & 15;
    int src = (row << 4) + (cc ^ (row & 7));
    __builtin_amdgcn_global_load_lds((as1u32*)(g + src * 8),
                                     (as3u32*)(s + c * 8), 16, 0, 0);
  }
}

// A-frag: row = lane&15, k = 8*(lane>>4)+e (contiguous 8 bf16). B-frag same on
// the "col" rows (NT). C/D: col = lane&15, row = (lane>>4)*4 + reg  [m89/m91].
__device__ inline void mfma_tile(const unsigned short* As, const unsigned short* Bs,
                                 f32x4 acc[4][4]){
  int tid = threadIdx.x;
  int w = tid >> 6, l = tid & 63;
  int wr = (w >> 1) * 64, wc = (w & 1) * 64;
  int lo = l & 15, hi = l >> 4;
  f32x4 zero = {0.f, 0.f, 0.f, 0.f};
  #pragma unroll
  for (int m = 0; m < 4; ++m)
    #pragma unroll
    for (int n = 0; n < 4; ++n) acc[m][n] = zero;
  #pragma unroll
  for (int kk = 0; kk < 4; ++kk){
    bf16x8 af[4], bfv[4];
    #pragma unroll
    for (int m = 0; m < 4; ++m){
      int row = wr + m * 16 + lo;
      af[m] = *(const bf16x8*)(As + row * 128 + ((kk * 4 + hi) ^ (row & 7)) * 8);
    }
    #pragma unroll
    for (int n = 0; n < 4; ++n){
      int row = wc + n * 16 + lo;
      bfv[n] = *(const bf16x8*)(Bs + row * 128 + ((kk * 4 + hi) ^ (row & 7)) * 8);
    }
    #pragma unroll
    for (int m = 0; m < 4; ++m)
      #pragma unroll
      for (int n = 0; n < 4; ++n)
        acc[m][n] = __builtin_amdgcn_mfma_f32_16x16x32_bf16(af[m], bfv[n], acc[m][n], 0, 0, 0);
  }
}

// ---------------- phase 2: lin1 + leaky + lin2 + sigmoid -> T, 1/T ----------------
__global__ __launch_bounds__(256) void k_lin(const unsigned short* __restrict__ hb,
    const unsigned short* __restrict__ W1b, const float* __restrict__ b1,
    const float* __restrict__ W2, const float* __restrict__ b2,
    float* __restrict__ Tw, float* __restrict__ rTw, float* __restrict__ Tpart){
  __shared__ __align__(16) unsigned short As[16384];
  __shared__ __align__(16) unsigned short Bs[16384];
  __shared__ float zpart[2][128];
  __shared__ float s4[4];
  int i0 = blockIdx.x * 128;
  stage_tile(hb + (size_t)i0 * 128, As);
  stage_tile(W1b, Bs);
  asm volatile("s_waitcnt vmcnt(0)" ::: "memory");
  __syncthreads();
  f32x4 acc[4][4];
  mfma_tile(As, Bs, acc);
  int tid = threadIdx.x, w = tid >> 6, l = tid & 63;
  int wrb = (w >> 1) * 64, wcb = (w & 1) * 64, lo = l & 15, hi = l >> 4;
  float w2v[4], b1v[4];
  #pragma unroll
  for (int n = 0; n < 4; ++n){ int col = wcb + n * 16 + lo; w2v[n] = W2[col]; b1v[n] = b1[col]; }
  #pragma unroll
  for (int m = 0; m < 4; ++m){
    #pragma unroll
    for (int q = 0; q < 4; ++q){
      float p = 0.f;
      #pragma unroll
      for (int n = 0; n < 4; ++n){
        float hv = acc[m][n][q] + b1v[n];
        hv = hv >= 0.f ? hv : 0.2f * hv;   // leaky_relu(0.2)
        p += hv * w2v[n];
      }
      p += __shfl_xor(p, 1); p += __shfl_xor(p, 2);
      p += __shfl_xor(p, 4); p += __shfl_xor(p, 8);
      if (lo == 0) zpart[w & 1][wrb + m * 16 + hi * 4 + q] = p;
    }
  }
  __syncthreads();
  float Tloc = 0.f;
  if (tid < 128){
    float z = zpart[0][tid] + zpart[1][tid] + b2[0];
    float s = 1.f / (1.f + __expf(-z));
    float T = 0.95f * (1.f - s) + 0.05f;
    Tw[i0 + tid] = T; rTw[i0 + tid] = 1.f / T;
    Tloc = T;
  }
  float v = Tloc;
  #pragma unroll
  for (int o = 32; o; o >>= 1) v += __shfl_xor(v, o);
  if ((tid & 63) == 0) s4[tid >> 6] = v;
  __syncthreads();
  if (tid == 0) Tpart[blockIdx.x] = s4[0] + s4[1] + s4[2] + s4[3];
}

// ---------------- phase 3: tot GEMM + exp row-reduce partials ----------------
__global__ __launch_bounds__(256) void k_tot(const unsigned short* __restrict__ f1b,
    const unsigned short* __restrict__ f2b, const float* __restrict__ rTw,
    float* __restrict__ totpart){
  __shared__ __align__(16) unsigned short As[16384];
  __shared__ __align__(16) unsigned short Bs[16384];
  __shared__ float rowacc[2][128];
  int bx = blockIdx.x, rt = bx >> 6, ct = bx & 63;
  stage_tile(f1b + (size_t)rt * 16384, As);
  stage_tile(f2b + (size_t)ct * 16384, Bs);
  asm volatile("s_waitcnt vmcnt(0)" ::: "memory");
  __syncthreads();
  f32x4 acc[4][4];
  mfma_tile(As, Bs, acc);
  int tid = threadIdx.x, w = tid >> 6, l = tid & 63;
  int wrb = (w >> 1) * 64, lo = l & 15, hi = l >> 4;
  int i0 = rt * 128;
  #pragma unroll
  for (int m = 0; m < 4; ++m){
    #pragma unroll
    for (int q = 0; q < 4; ++q){
      int lr = wrb + m * 16 + hi * 4 + q;
      float r = rTw[i0 + lr];
      float p = __expf(acc[m][0][q] * r) + __expf(acc[m][1][q] * r)
              + __expf(acc[m][2][q] * r) + __expf(acc[m][3][q] * r);
      p += __shfl_xor(p, 1); p += __shfl_xor(p, 2);
      p += __shfl_xor(p, 4); p += __shfl_xor(p, 8);
      if (lo == 0) rowacc[w & 1][lr] = p;
    }
  }
  __syncthreads();
  if (tid < 128) totpart[(size_t)ct * B_TOT + i0 + tid] = rowacc[0][tid] + rowacc[1][tid];
}

// ---------------- phase 4: pos_rating writer (268 MB, coalesced float4) ----------------
__global__ __launch_bounds__(256) void k_pr(const float* __restrict__ posw,
    const float* __restrict__ rTw, float* __restrict__ out){
  int i = blockIdx.x;
  float r = rTw[i];
  float4* o4 = (float4*)(out + (size_t)i * B_TOT);
  const float4* p4 = (const float4*)posw;
  for (int c = threadIdx.x; c < 2048; c += 256){
    float4 p = p4[c];
    float4 e;
    e.x = __expf(p.x * r); e.y = __expf(p.y * r);
    e.z = __expf(p.z * r); e.w = __expf(p.w * r);
    o4[c] = e;
  }
}

// ---------------- phase 5: tot_rating reduce + temp mean ----------------
__global__ __launch_bounds__(256) void k_red(const float* __restrict__ totpart,
    const float* __restrict__ Tpart, float* __restrict__ out){
  int i = blockIdx.x * 256 + threadIdx.x;   // grid 32 -> 8192 rows
  float s = 0.f;
  for (int ct = 0; ct < 64; ++ct) s += totpart[(size_t)ct * B_TOT + i];
  out[OUT_TOT + i] = s;
  if (blockIdx.x == 0 && threadIdx.x < 64){
    float v = Tpart[threadIdx.x];
    #pragma unroll
    for (int o = 32; o; o >>= 1) v += __shfl_xor(v, o);
    if (threadIdx.x == 0) out[OUT_AVG] = v * (1.0f / 8192.0f);
  }
}

extern "C" void kernel_launch(void* const* d_in, const int* in_sizes, int n_in,
                              void* d_out, int out_size, void* d_ws, size_t ws_size,
                              hipStream_t stream){
  const float* x1 = (const float*)d_in[0];
  const float* x2 = (const float*)d_in[1];
  const int*   i1 = (const int*)d_in[2];
  const int*   i2 = (const int*)d_in[3];
  const float* W1 = (const float*)d_in[4];
  const float* b1 = (const float*)d_in[5];
  const float* W2 = (const float*)d_in[6];
  const float* b2 = (const float*)d_in[7];
  float* out = (float*)d_out;
  char* ws = (char*)d_ws;
  // ws layout (bytes), total ~8.5 MB
  unsigned short* hb   = (unsigned short*)(ws);              // 2 MB
  unsigned short* f1b  = (unsigned short*)(ws + 2097152);    // 2 MB
  unsigned short* f2b  = (unsigned short*)(ws + 4194304);    // 2 MB
  unsigned short* W1b  = (unsigned short*)(ws + 6291456);    // 32 KB
  float* posw  = (float*)(ws + 6324224);                     // 32 KB
  float* Tw    = (float*)(ws + 6356992);                     // 32 KB
  float* rTw   = (float*)(ws + 6389760);                     // 32 KB
  float* Tpart = (float*)(ws + 6422528);                     // 256 B
  float* totpart = (float*)(ws + 6422784);                   // 2 MB

  hipLaunchKernelGGL(k_convw, dim3(64),   dim3(256), 0, stream, W1, W1b);
  hipLaunchKernelGGL(k_feat,  dim3(8192), dim3(128), 0, stream, x1, x2, i1, i2, f1b, f2b, hb, posw);
  hipLaunchKernelGGL(k_lin,   dim3(64),   dim3(256), 0, stream, hb, W1b, b1, W2, b2, Tw, rTw, Tpart);
  hipLaunchKernelGGL(k_tot,   dim3(4096), dim3(256), 0, stream, f1b, f2b, rTw, totpart);
  hipLaunchKernelGGL(k_pr,    dim3(8192), dim3(256), 0, stream, posw, rTw, out);
  hipLaunchKernelGGL(k_red,   dim3(32),   dim3(256), 0, stream, totpart, Tpart, out);
}

// Round 2
// 104.090 us; speedup vs baseline: 1.2081x; 1.2081x over previous
//
#include <hip/hip_runtime.h>
#include <stdint.h>

typedef __bf16 bf16x8 __attribute__((ext_vector_type(8)));
typedef float f32x4 __attribute__((ext_vector_type(4)));
typedef __attribute__((address_space(3))) uint32_t as3u32;
typedef const __attribute__((address_space(1))) uint32_t as1u32;

#define B_TOT 8192
#define DD 128
#define OUT_TOT 67108864UL
#define OUT_AVG 67117056UL

__device__ inline unsigned short f2bf(float x){
  union { float f; uint32_t u; } v; v.f = x;
  return (unsigned short)((v.u + 0x7fffu + ((v.u >> 16) & 1u)) >> 16);
}

// ---------------- phase 1: gather + normalize + h + pos ----------------
__device__ inline float bsum128(float v, volatile float* s2){
  #pragma unroll
  for (int o = 32; o; o >>= 1) v += __shfl_xor(v, o);
  __syncthreads();
  if ((threadIdx.x & 63) == 0) s2[threadIdx.x >> 6] = v;
  __syncthreads();
  return s2[0] + s2[1];
}

__global__ __launch_bounds__(128) void k_feat(const float* __restrict__ x1,
    const float* __restrict__ x2, const int* __restrict__ i1a, const int* __restrict__ i2a,
    unsigned short* __restrict__ f1b, unsigned short* __restrict__ f2b,
    unsigned short* __restrict__ hb, float* __restrict__ posw){
  __shared__ float s2[2];
  int b = blockIdx.x, t = threadIdx.x;
  size_t r1 = (size_t)i1a[b] * DD, r2 = (size_t)i2a[b] * DD;
  float v1 = x1[r1 + t], v2 = x2[r2 + t];
  float n1 = sqrtf(bsum128(v1 * v1, s2));
  float f1 = v1 / fmaxf(n1, 1e-12f);
  float n2 = sqrtf(bsum128(v2 * v2, s2));
  float f2 = v2 / fmaxf(n2, 1e-12f);
  float h = f1 * f2;
  float pos = bsum128(h, s2);
  int o = b * DD + t;
  f1b[o] = f2bf(f1); f2b[o] = f2bf(f2); hb[o] = f2bf(h);
  if (t == 0) posw[b] = pos;
}

// ---------------- shared GEMM tile machinery (128x128, K=128, NT) ----------------
// LDS layout: row-major [128][128] bf16, 16B-chunk XOR swizzle:
// LDS chunk (row, cc) holds global chunk (row, cc ^ (row&7)).
// global_load_lds writes LDS linearly -> pre-swizzle the per-lane GLOBAL src.
__device__ inline void stage_tile(const unsigned short* g, unsigned short* s){
  int tid = threadIdx.x;
  #pragma unroll
  for (int it = 0; it < 8; ++it){
    int c = tid + it * 256;          // 2048 chunks of 16B
    int row = c >> 4, cc = c & 15;
    int src = (row << 4) + (cc ^ (row & 7));
    __builtin_amdgcn_global_load_lds((as1u32*)(g + src * 8),
                                     (as3u32*)(s + c * 8), 16, 0, 0);
  }
}

// A-frag: row = lane&15, k = 8*(lane>>4)+e. C/D: col = lane&15, row=(lane>>4)*4+reg.
__device__ inline void mfma_tile(const unsigned short* As, const unsigned short* Bs,
                                 f32x4 acc[4][4]){
  int tid = threadIdx.x;
  int w = tid >> 6, l = tid & 63;
  int wr = (w >> 1) * 64, wc = (w & 1) * 64;
  int lo = l & 15, hi = l >> 4;
  f32x4 zero = {0.f, 0.f, 0.f, 0.f};
  #pragma unroll
  for (int m = 0; m < 4; ++m)
    #pragma unroll
    for (int n = 0; n < 4; ++n) acc[m][n] = zero;
  #pragma unroll
  for (int kk = 0; kk < 4; ++kk){
    bf16x8 af[4], bfv[4];
    #pragma unroll
    for (int m = 0; m < 4; ++m){
      int row = wr + m * 16 + lo;
      af[m] = *(const bf16x8*)(As + row * 128 + ((kk * 4 + hi) ^ (row & 7)) * 8);
    }
    #pragma unroll
    for (int n = 0; n < 4; ++n){
      int row = wc + n * 16 + lo;
      bfv[n] = *(const bf16x8*)(Bs + row * 128 + ((kk * 4 + hi) ^ (row & 7)) * 8);
    }
    #pragma unroll
    for (int m = 0; m < 4; ++m)
      #pragma unroll
      for (int n = 0; n < 4; ++n)
        acc[m][n] = __builtin_amdgcn_mfma_f32_16x16x32_bf16(af[m], bfv[n], acc[m][n], 0, 0, 0);
  }
}

// ---------------- phase 2: lin1 + leaky + lin2 + sigmoid -> T, 1/T ----------------
__global__ __launch_bounds__(256) void k_lin(const unsigned short* __restrict__ hb,
    const float* __restrict__ W1, const float* __restrict__ b1,
    const float* __restrict__ W2, const float* __restrict__ b2,
    float* __restrict__ Tw, float* __restrict__ rTw, float* __restrict__ Tpart){
  __shared__ __align__(16) unsigned short As[16384];
  __shared__ __align__(16) unsigned short Bs[16384];
  __shared__ float zpart[2][128];
  __shared__ float s4[4];
  int i0 = blockIdx.x * 128;
  int tid = threadIdx.x;
  stage_tile(hb + (size_t)i0 * 128, As);
  // stage W1 (f32 global) -> Bs (bf16), same swizzle, reg-staged ds_write
  #pragma unroll
  for (int it = 0; it < 8; ++it){
    int c = tid + it * 256;
    int row = c >> 4, cc = c & 15;
    int src = (row << 4) + (cc ^ (row & 7));
    const float4* g4 = (const float4*)(W1 + src * 8);
    float4 a = g4[0], b = g4[1];
    unsigned short t8[8];
    t8[0] = f2bf(a.x); t8[1] = f2bf(a.y); t8[2] = f2bf(a.z); t8[3] = f2bf(a.w);
    t8[4] = f2bf(b.x); t8[5] = f2bf(b.y); t8[6] = f2bf(b.z); t8[7] = f2bf(b.w);
    *(uint4*)(Bs + c * 8) = *(uint4*)t8;
  }
  asm volatile("s_waitcnt vmcnt(0)" ::: "memory");
  __syncthreads();
  f32x4 acc[4][4];
  mfma_tile(As, Bs, acc);
  int w = tid >> 6, l = tid & 63;
  int wrb = (w >> 1) * 64, wcb = (w & 1) * 64, lo = l & 15, hi = l >> 4;
  float w2v[4], b1v[4];
  #pragma unroll
  for (int n = 0; n < 4; ++n){ int col = wcb + n * 16 + lo; w2v[n] = W2[col]; b1v[n] = b1[col]; }
  #pragma unroll
  for (int m = 0; m < 4; ++m){
    #pragma unroll
    for (int q = 0; q < 4; ++q){
      float p = 0.f;
      #pragma unroll
      for (int n = 0; n < 4; ++n){
        float hv = acc[m][n][q] + b1v[n];
        hv = hv >= 0.f ? hv : 0.2f * hv;   // leaky_relu(0.2)
        p += hv * w2v[n];
      }
      p += __shfl_xor(p, 1); p += __shfl_xor(p, 2);
      p += __shfl_xor(p, 4); p += __shfl_xor(p, 8);
      if (lo == 0) zpart[w & 1][wrb + m * 16 + hi * 4 + q] = p;
    }
  }
  __syncthreads();
  float Tloc = 0.f;
  if (tid < 128){
    float z = zpart[0][tid] + zpart[1][tid] + b2[0];
    float s = 1.f / (1.f + __expf(-z));
    float T = 0.95f * (1.f - s) + 0.05f;
    Tw[i0 + tid] = T; rTw[i0 + tid] = 1.f / T;
    Tloc = T;
  }
  float v = Tloc;
  #pragma unroll
  for (int o = 32; o; o >>= 1) v += __shfl_xor(v, o);
  if ((tid & 63) == 0) s4[tid >> 6] = v;
  __syncthreads();
  if (tid == 0) Tpart[blockIdx.x] = s4[0] + s4[1] + s4[2] + s4[3];
}

// ------- phase 3: tot GEMM + exp row-reduce partials + pos_rating tile write -------
__global__ __launch_bounds__(256) void k_tot(const unsigned short* __restrict__ f1b,
    const unsigned short* __restrict__ f2b, const float* __restrict__ rTw,
    const float* __restrict__ posw, float* __restrict__ totpart,
    float* __restrict__ out){
  __shared__ __align__(16) unsigned short As[16384];
  __shared__ __align__(16) unsigned short Bs[16384];
  __shared__ float rowacc[2][128];
  __shared__ float posS[128];
  __shared__ float rS[128];
  int bx = blockIdx.x, rt = bx >> 6, ct = bx & 63;
  stage_tile(f1b + (size_t)rt * 16384, As);
  stage_tile(f2b + (size_t)ct * 16384, Bs);
  asm volatile("s_waitcnt vmcnt(0)" ::: "memory");
  __syncthreads();
  f32x4 acc[4][4];
  mfma_tile(As, Bs, acc);
  int tid = threadIdx.x, w = tid >> 6, l = tid & 63;
  int wrb = (w >> 1) * 64, lo = l & 15, hi = l >> 4;
  int i0 = rt * 128;
  if (tid < 128) posS[tid] = posw[ct * 128 + tid];
  else           rS[tid - 128] = rTw[i0 + tid - 128];
  #pragma unroll
  for (int m = 0; m < 4; ++m){
    #pragma unroll
    for (int q = 0; q < 4; ++q){
      int lr = wrb + m * 16 + hi * 4 + q;
      float r = rTw[i0 + lr];
      float p = __expf(acc[m][0][q] * r) + __expf(acc[m][1][q] * r)
              + __expf(acc[m][2][q] * r) + __expf(acc[m][3][q] * r);
      p += __shfl_xor(p, 1); p += __shfl_xor(p, 2);
      p += __shfl_xor(p, 4); p += __shfl_xor(p, 8);
      if (lo == 0) rowacc[w & 1][lr] = p;
    }
  }
  __syncthreads();
  if (tid < 128) totpart[(size_t)ct * B_TOT + i0 + tid] = rowacc[0][tid] + rowacc[1][tid];
  // pos_rating 128x128 tile: rows i0.., cols ct*128.. ; 512B segments per row
  int c0 = (tid & 31) * 4;
  float4 p4 = *(const float4*)&posS[c0];
  #pragma unroll
  for (int pass = 0; pass < 16; ++pass){
    int row = pass * 8 + (tid >> 5);
    float r = rS[row];
    float4 e;
    e.x = __expf(p4.x * r); e.y = __expf(p4.y * r);
    e.z = __expf(p4.z * r); e.w = __expf(p4.w * r);
    *(float4*)(out + (size_t)(i0 + row) * B_TOT + ct * 128 + c0) = e;
  }
}

// ---------------- phase 4: tot_rating reduce + temp mean ----------------
__global__ __launch_bounds__(256) void k_red(const float* __restrict__ totpart,
    const float* __restrict__ Tpart, float* __restrict__ out){
  int i = blockIdx.x * 256 + threadIdx.x;   // grid 32 -> 8192 rows
  float s = 0.f;
  for (int ct = 0; ct < 64; ++ct) s += totpart[(size_t)ct * B_TOT + i];
  out[OUT_TOT + i] = s;
  if (blockIdx.x == 0 && threadIdx.x < 64){
    float v = Tpart[threadIdx.x];
    #pragma unroll
    for (int o = 32; o; o >>= 1) v += __shfl_xor(v, o);
    if (threadIdx.x == 0) out[OUT_AVG] = v * (1.0f / 8192.0f);
  }
}

extern "C" void kernel_launch(void* const* d_in, const int* in_sizes, int n_in,
                              void* d_out, int out_size, void* d_ws, size_t ws_size,
                              hipStream_t stream){
  const float* x1 = (const float*)d_in[0];
  const float* x2 = (const float*)d_in[1];
  const int*   i1 = (const int*)d_in[2];
  const int*   i2 = (const int*)d_in[3];
  const float* W1 = (const float*)d_in[4];
  const float* b1 = (const float*)d_in[5];
  const float* W2 = (const float*)d_in[6];
  const float* b2 = (const float*)d_in[7];
  float* out = (float*)d_out;
  char* ws = (char*)d_ws;
  unsigned short* hb   = (unsigned short*)(ws);              // 2 MB
  unsigned short* f1b  = (unsigned short*)(ws + 2097152);    // 2 MB
  unsigned short* f2b  = (unsigned short*)(ws + 4194304);    // 2 MB
  float* posw  = (float*)(ws + 6291456);                     // 32 KB
  float* Tw    = (float*)(ws + 6324224);                     // 32 KB
  float* rTw   = (float*)(ws + 6356992);                     // 32 KB
  float* Tpart = (float*)(ws + 6389760);                     // 256 B
  float* totpart = (float*)(ws + 6390016);                   // 2 MB

  hipLaunchKernelGGL(k_feat,  dim3(8192), dim3(128), 0, stream, x1, x2, i1, i2, f1b, f2b, hb, posw);
  hipLaunchKernelGGL(k_lin,   dim3(64),   dim3(256), 0, stream, hb, W1, b1, W2, b2, Tw, rTw, Tpart);
  hipLaunchKernelGGL(k_tot,   dim3(4096), dim3(256), 0, stream, f1b, f2b, rTw, posw, totpart, out);
  hipLaunchKernelGGL(k_red,   dim3(32),   dim3(256), 0, stream, totpart, Tpart, out);
}

// Round 4
// 100.835 us; speedup vs baseline: 1.2471x; 1.0323x over previous
//
#include <hip/hip_runtime.h>
#include <stdint.h>

typedef __bf16 bf16x8 __attribute__((ext_vector_type(8)));
typedef float f32x4 __attribute__((ext_vector_type(4)));
typedef __attribute__((address_space(3))) uint32_t as3u32;
typedef const __attribute__((address_space(1))) uint32_t as1u32;

#define B_TOT 8192
#define DD 128
#define OUT_TOT 67108864UL
#define OUT_AVG 67117056UL

__device__ inline unsigned short f2bf(float x){
  union { float f; uint32_t u; } v; v.f = x;
  return (unsigned short)((v.u + 0x7fffu + ((v.u >> 16) & 1u)) >> 16);
}

// ---------------- phase 1: gather + normalize + h + pos ----------------
__device__ inline float bsum128(float v, volatile float* s2){
  #pragma unroll
  for (int o = 32; o; o >>= 1) v += __shfl_xor(v, o);
  __syncthreads();
  if ((threadIdx.x & 63) == 0) s2[threadIdx.x >> 6] = v;
  __syncthreads();
  return s2[0] + s2[1];
}

__global__ __launch_bounds__(128) void k_feat(const float* __restrict__ x1,
    const float* __restrict__ x2, const int* __restrict__ i1a, const int* __restrict__ i2a,
    unsigned short* __restrict__ f1b, unsigned short* __restrict__ f2b,
    unsigned short* __restrict__ hb, float* __restrict__ posw){
  __shared__ float s2[2];
  int b = blockIdx.x, t = threadIdx.x;
  size_t r1 = (size_t)i1a[b] * DD, r2 = (size_t)i2a[b] * DD;
  float v1 = x1[r1 + t], v2 = x2[r2 + t];
  float n1 = sqrtf(bsum128(v1 * v1, s2));
  float f1 = v1 / fmaxf(n1, 1e-12f);
  float n2 = sqrtf(bsum128(v2 * v2, s2));
  float f2 = v2 / fmaxf(n2, 1e-12f);
  float h = f1 * f2;
  float pos = bsum128(h, s2);
  int o = b * DD + t;
  f1b[o] = f2bf(f1); f2b[o] = f2bf(f2); hb[o] = f2bf(h);
  if (t == 0) posw[b] = pos;
}

// ---------------- shared GEMM tile machinery (128x128, K=128, NT) ----------------
// LDS layout: row-major [128][128] bf16, 16B-chunk XOR swizzle:
// LDS chunk (row, cc) holds global chunk (row, cc ^ (row&7)).
// global_load_lds writes LDS linearly -> pre-swizzle the per-lane GLOBAL src.
__device__ inline void stage_tile(const unsigned short* g, unsigned short* s){
  int tid = threadIdx.x;
  #pragma unroll
  for (int it = 0; it < 8; ++it){
    int c = tid + it * 256;          // 2048 chunks of 16B
    int row = c >> 4, cc = c & 15;
    int src = (row << 4) + (cc ^ (row & 7));
    __builtin_amdgcn_global_load_lds((as1u32*)(g + src * 8),
                                     (as3u32*)(s + c * 8), 16, 0, 0);
  }
}

// A-frag: row = lane&15, k = 8*(lane>>4)+e. C/D: col = lane&15, row=(lane>>4)*4+reg.
__device__ inline void mfma_tile(const unsigned short* As, const unsigned short* Bs,
                                 f32x4 acc[4][4]){
  int tid = threadIdx.x;
  int w = tid >> 6, l = tid & 63;
  int wr = (w >> 1) * 64, wc = (w & 1) * 64;
  int lo = l & 15, hi = l >> 4;
  f32x4 zero = {0.f, 0.f, 0.f, 0.f};
  #pragma unroll
  for (int m = 0; m < 4; ++m)
    #pragma unroll
    for (int n = 0; n < 4; ++n) acc[m][n] = zero;
  #pragma unroll
  for (int kk = 0; kk < 4; ++kk){
    bf16x8 af[4], bfv[4];
    #pragma unroll
    for (int m = 0; m < 4; ++m){
      int row = wr + m * 16 + lo;
      af[m] = *(const bf16x8*)(As + row * 128 + ((kk * 4 + hi) ^ (row & 7)) * 8);
    }
    #pragma unroll
    for (int n = 0; n < 4; ++n){
      int row = wc + n * 16 + lo;
      bfv[n] = *(const bf16x8*)(Bs + row * 128 + ((kk * 4 + hi) ^ (row & 7)) * 8);
    }
    #pragma unroll
    for (int m = 0; m < 4; ++m)
      #pragma unroll
      for (int n = 0; n < 4; ++n)
        acc[m][n] = __builtin_amdgcn_mfma_f32_16x16x32_bf16(af[m], bfv[n], acc[m][n], 0, 0, 0);
  }
}

// ---------------- phase 2: lin1 + leaky + lin2 + sigmoid -> T, 1/T ----------------
__global__ __launch_bounds__(256) void k_lin(const unsigned short* __restrict__ hb,
    const float* __restrict__ W1, const float* __restrict__ b1,
    const float* __restrict__ W2, const float* __restrict__ b2,
    float* __restrict__ Tw, float* __restrict__ rTw, float* __restrict__ Tpart){
  __shared__ __align__(16) unsigned short As[16384];
  __shared__ __align__(16) unsigned short Bs[16384];
  __shared__ float zpart[2][128];
  __shared__ float s4[4];
  int i0 = blockIdx.x * 128;
  int tid = threadIdx.x;
  stage_tile(hb + (size_t)i0 * 128, As);
  // stage W1 (f32 global) -> Bs (bf16), same swizzle, reg-staged ds_write
  #pragma unroll
  for (int it = 0; it < 8; ++it){
    int c = tid + it * 256;
    int row = c >> 4, cc = c & 15;
    int src = (row << 4) + (cc ^ (row & 7));
    const float4* g4 = (const float4*)(W1 + src * 8);
    float4 a = g4[0], b = g4[1];
    unsigned short t8[8];
    t8[0] = f2bf(a.x); t8[1] = f2bf(a.y); t8[2] = f2bf(a.z); t8[3] = f2bf(a.w);
    t8[4] = f2bf(b.x); t8[5] = f2bf(b.y); t8[6] = f2bf(b.z); t8[7] = f2bf(b.w);
    *(uint4*)(Bs + c * 8) = *(uint4*)t8;
  }
  asm volatile("s_waitcnt vmcnt(0)" ::: "memory");
  __syncthreads();
  f32x4 acc[4][4];
  mfma_tile(As, Bs, acc);
  int w = tid >> 6, l = tid & 63;
  int wrb = (w >> 1) * 64, wcb = (w & 1) * 64, lo = l & 15, hi = l >> 4;
  float w2v[4], b1v[4];
  #pragma unroll
  for (int n = 0; n < 4; ++n){ int col = wcb + n * 16 + lo; w2v[n] = W2[col]; b1v[n] = b1[col]; }
  #pragma unroll
  for (int m = 0; m < 4; ++m){
    #pragma unroll
    for (int q = 0; q < 4; ++q){
      float p = 0.f;
      #pragma unroll
      for (int n = 0; n < 4; ++n){
        float hv = acc[m][n][q] + b1v[n];
        hv = hv >= 0.f ? hv : 0.2f * hv;   // leaky_relu(0.2)
        p += hv * w2v[n];
      }
      p += __shfl_xor(p, 1); p += __shfl_xor(p, 2);
      p += __shfl_xor(p, 4); p += __shfl_xor(p, 8);
      if (lo == 0) zpart[w & 1][wrb + m * 16 + hi * 4 + q] = p;
    }
  }
  __syncthreads();
  float Tloc = 0.f;
  if (tid < 128){
    float z = zpart[0][tid] + zpart[1][tid] + b2[0];
    float s = 1.f / (1.f + __expf(-z));
    float T = 0.95f * (1.f - s) + 0.05f;
    Tw[i0 + tid] = T; rTw[i0 + tid] = 1.f / T;
    Tloc = T;
  }
  float v = Tloc;
  #pragma unroll
  for (int o = 32; o; o >>= 1) v += __shfl_xor(v, o);
  if ((tid & 63) == 0) s4[tid >> 6] = v;
  __syncthreads();
  if (tid == 0) Tpart[blockIdx.x] = s4[0] + s4[1] + s4[2] + s4[3];
}

// ------- phase 3: tot GEMM + exp row-reduce partials + pos_rating tile write -------
__global__ __launch_bounds__(256) void k_tot(const unsigned short* __restrict__ f1b,
    const unsigned short* __restrict__ f2b, const float* __restrict__ rTw,
    const float* __restrict__ posw, float* __restrict__ totpart,
    float* __restrict__ out){
  __shared__ __align__(16) unsigned short As[16384];
  __shared__ __align__(16) unsigned short Bs[16384];
  __shared__ float rowacc[2][128];
  __shared__ float posS[128];
  __shared__ float rS[128];
  // bijective XCD-chunked swizzle (grid 4096 % 8 == 0): XCD k owns rt in
  // [8k, 8k+8); consecutive blocks on an XCD share the A tile (L2-hot).
  int bx = (blockIdx.x & 7) * 512 + (blockIdx.x >> 3);
  int rt = bx >> 6, ct = bx & 63;
  stage_tile(f1b + (size_t)rt * 16384, As);
  stage_tile(f2b + (size_t)ct * 16384, Bs);
  asm volatile("s_waitcnt vmcnt(0)" ::: "memory");
  __syncthreads();
  f32x4 acc[4][4];
  mfma_tile(As, Bs, acc);
  int tid = threadIdx.x, w = tid >> 6, l = tid & 63;
  int wrb = (w >> 1) * 64, lo = l & 15, hi = l >> 4;
  int i0 = rt * 128;
  if (tid < 128) posS[tid] = posw[ct * 128 + tid];
  else           rS[tid - 128] = rTw[i0 + tid - 128];
  #pragma unroll
  for (int m = 0; m < 4; ++m){
    #pragma unroll
    for (int q = 0; q < 4; ++q){
      int lr = wrb + m * 16 + hi * 4 + q;
      float r = rTw[i0 + lr];
      float p = __expf(acc[m][0][q] * r) + __expf(acc[m][1][q] * r)
              + __expf(acc[m][2][q] * r) + __expf(acc[m][3][q] * r);
      p += __shfl_xor(p, 1); p += __shfl_xor(p, 2);
      p += __shfl_xor(p, 4); p += __shfl_xor(p, 8);
      if (lo == 0) rowacc[w & 1][lr] = p;
    }
  }
  __syncthreads();
  if (tid < 128) totpart[(size_t)ct * B_TOT + i0 + tid] = rowacc[0][tid] + rowacc[1][tid];
  // pos_rating 128x128 tile, non-temporal (streaming, never re-read):
  // keeps f1b/f2b resident in L2 instead of being thrashed by 268 MB of writes.
  int c0 = (tid & 31) * 4;
  f32x4 p4 = *(const f32x4*)&posS[c0];
  #pragma unroll
  for (int pass = 0; pass < 16; ++pass){
    int row = pass * 8 + (tid >> 5);
    float r = rS[row];
    f32x4 e;
    e.x = __expf(p4.x * r); e.y = __expf(p4.y * r);
    e.z = __expf(p4.z * r); e.w = __expf(p4.w * r);
    __builtin_nontemporal_store(e, (f32x4*)(out + (size_t)(i0 + row) * B_TOT + ct * 128 + c0));
  }
}

// ---------------- phase 4: tot_rating reduce + temp mean ----------------
__global__ __launch_bounds__(256) void k_red(const float* __restrict__ totpart,
    const float* __restrict__ Tpart, float* __restrict__ out){
  int i = blockIdx.x * 256 + threadIdx.x;   // grid 32 -> 8192 rows
  float s = 0.f;
  #pragma unroll 8
  for (int ct = 0; ct < 64; ++ct) s += totpart[(size_t)ct * B_TOT + i];
  out[OUT_TOT + i] = s;
  if (blockIdx.x == 0 && threadIdx.x < 64){
    float v = Tpart[threadIdx.x];
    #pragma unroll
    for (int o = 32; o; o >>= 1) v += __shfl_xor(v, o);
    if (threadIdx.x == 0) out[OUT_AVG] = v * (1.0f / 8192.0f);
  }
}

extern "C" void kernel_launch(void* const* d_in, const int* in_sizes, int n_in,
                              void* d_out, int out_size, void* d_ws, size_t ws_size,
                              hipStream_t stream){
  const float* x1 = (const float*)d_in[0];
  const float* x2 = (const float*)d_in[1];
  const int*   i1 = (const int*)d_in[2];
  const int*   i2 = (const int*)d_in[3];
  const float* W1 = (const float*)d_in[4];
  const float* b1 = (const float*)d_in[5];
  const float* W2 = (const float*)d_in[6];
  const float* b2 = (const float*)d_in[7];
  float* out = (float*)d_out;
  char* ws = (char*)d_ws;
  unsigned short* hb   = (unsigned short*)(ws);              // 2 MB
  unsigned short* f1b  = (unsigned short*)(ws + 2097152);    // 2 MB
  unsigned short* f2b  = (unsigned short*)(ws + 4194304);    // 2 MB
  float* posw  = (float*)(ws + 6291456);                     // 32 KB
  float* Tw    = (float*)(ws + 6324224);                     // 32 KB
  float* rTw   = (float*)(ws + 6356992);                     // 32 KB
  float* Tpart = (float*)(ws + 6389760);                     // 256 B
  float* totpart = (float*)(ws + 6390016);                   // 2 MB

  hipLaunchKernelGGL(k_feat,  dim3(8192), dim3(128), 0, stream, x1, x2, i1, i2, f1b, f2b, hb, posw);
  hipLaunchKernelGGL(k_lin,   dim3(64),   dim3(256), 0, stream, hb, W1, b1, W2, b2, Tw, rTw, Tpart);
  hipLaunchKernelGGL(k_tot,   dim3(4096), dim3(256), 0, stream, f1b, f2b, rTw, posw, totpart, out);
  hipLaunchKernelGGL(k_red,   dim3(32),   dim3(256), 0, stream, totpart, Tpart, out);
}

// Round 5
// 95.356 us; speedup vs baseline: 1.3188x; 1.0575x over previous
//
#include <hip/hip_runtime.h>
#include <stdint.h>

typedef __bf16 bf16x8 __attribute__((ext_vector_type(8)));
typedef float f32x4 __attribute__((ext_vector_type(4)));
typedef __attribute__((address_space(3))) uint32_t as3u32;
typedef const __attribute__((address_space(1))) uint32_t as1u32;

#define B_TOT 8192
#define DD 128
#define OUT_TOT 67108864UL
#define OUT_AVG 67117056UL

__device__ inline unsigned short f2bf(float x){
  union { float f; uint32_t u; } v; v.f = x;
  return (unsigned short)((v.u + 0x7fffu + ((v.u >> 16) & 1u)) >> 16);
}

// ---------------- phase 1: gather + normalize + h + pos (+ zero accumulators) ----
__device__ inline float bsum128(float v, volatile float* s2){
  #pragma unroll
  for (int o = 32; o; o >>= 1) v += __shfl_xor(v, o);
  __syncthreads();
  if ((threadIdx.x & 63) == 0) s2[threadIdx.x >> 6] = v;
  __syncthreads();
  return s2[0] + s2[1];
}

__global__ __launch_bounds__(128) void k_feat(const float* __restrict__ x1,
    const float* __restrict__ x2, const int* __restrict__ i1a, const int* __restrict__ i2a,
    unsigned short* __restrict__ f1b, unsigned short* __restrict__ f2b,
    unsigned short* __restrict__ hb, float* __restrict__ posw, float* __restrict__ out){
  __shared__ float s2[2];
  int b = blockIdx.x, t = threadIdx.x;
  int gid = b * 128 + t;
  if (gid <= 8192) out[OUT_TOT + gid] = 0.f;   // zero tot_rating accum + avg slot
  size_t r1 = (size_t)i1a[b] * DD, r2 = (size_t)i2a[b] * DD;
  float v1 = x1[r1 + t], v2 = x2[r2 + t];
  float n1 = sqrtf(bsum128(v1 * v1, s2));
  float f1 = v1 / fmaxf(n1, 1e-12f);
  float n2 = sqrtf(bsum128(v2 * v2, s2));
  float f2 = v2 / fmaxf(n2, 1e-12f);
  float h = f1 * f2;
  float pos = bsum128(h, s2);
  int o = b * DD + t;
  f1b[o] = f2bf(f1); f2b[o] = f2bf(f2); hb[o] = f2bf(h);
  if (t == 0) posw[b] = pos;
}

// ---------------- shared staging (128x128 bf16 tile, XOR-swizzled) ----------------
// LDS chunk (row, cc) holds global chunk (row, cc ^ (row&7)); global_load_lds
// writes LDS linearly -> pre-swizzle the per-lane GLOBAL source (rule #21).
__device__ inline void stage_tile(const unsigned short* g, unsigned short* s){
  int tid = threadIdx.x;
  #pragma unroll
  for (int it = 0; it < 8; ++it){
    int c = tid + it * 256;          // 2048 chunks of 16B
    int row = c >> 4, cc = c & 15;
    int src = (row << 4) + (cc ^ (row & 7));
    __builtin_amdgcn_global_load_lds((as1u32*)(g + src * 8),
                                     (as3u32*)(s + c * 8), 16, 0, 0);
  }
}

// A-frag: row = lane&15, k = 8*(lane>>4)+e. C/D: col = lane&15, row=(lane>>4)*4+reg.
__device__ inline void mfma_tile(const unsigned short* As, const unsigned short* Bs,
                                 f32x4 acc[4][4]){
  int tid = threadIdx.x;
  int w = tid >> 6, l = tid & 63;
  int wr = (w >> 1) * 64, wc = (w & 1) * 64;
  int lo = l & 15, hi = l >> 4;
  f32x4 zero = {0.f, 0.f, 0.f, 0.f};
  #pragma unroll
  for (int m = 0; m < 4; ++m)
    #pragma unroll
    for (int n = 0; n < 4; ++n) acc[m][n] = zero;
  #pragma unroll
  for (int kk = 0; kk < 4; ++kk){
    bf16x8 af[4], bfv[4];
    #pragma unroll
    for (int m = 0; m < 4; ++m){
      int row = wr + m * 16 + lo;
      af[m] = *(const bf16x8*)(As + row * 128 + ((kk * 4 + hi) ^ (row & 7)) * 8);
    }
    #pragma unroll
    for (int n = 0; n < 4; ++n){
      int row = wc + n * 16 + lo;
      bfv[n] = *(const bf16x8*)(Bs + row * 128 + ((kk * 4 + hi) ^ (row & 7)) * 8);
    }
    #pragma unroll
    for (int m = 0; m < 4; ++m)
      #pragma unroll
      for (int n = 0; n < 4; ++n)
        acc[m][n] = __builtin_amdgcn_mfma_f32_16x16x32_bf16(af[m], bfv[n], acc[m][n], 0, 0, 0);
  }
}

// ---------------- phase 2: lin1 + leaky + lin2 + sigmoid -> rT, temp-mean -------
__global__ __launch_bounds__(256) void k_lin(const unsigned short* __restrict__ hb,
    const float* __restrict__ W1, const float* __restrict__ b1,
    const float* __restrict__ W2, const float* __restrict__ b2,
    float* __restrict__ rTw, float* __restrict__ out){
  __shared__ __align__(16) unsigned short As[16384];
  __shared__ __align__(16) unsigned short Bs[16384];
  __shared__ float zpart[2][128];
  __shared__ float s4[4];
  int i0 = blockIdx.x * 128;
  int tid = threadIdx.x;
  stage_tile(hb + (size_t)i0 * 128, As);
  #pragma unroll
  for (int it = 0; it < 8; ++it){
    int c = tid + it * 256;
    int row = c >> 4, cc = c & 15;
    int src = (row << 4) + (cc ^ (row & 7));
    const float4* g4 = (const float4*)(W1 + src * 8);
    float4 a = g4[0], b = g4[1];
    unsigned short t8[8];
    t8[0] = f2bf(a.x); t8[1] = f2bf(a.y); t8[2] = f2bf(a.z); t8[3] = f2bf(a.w);
    t8[4] = f2bf(b.x); t8[5] = f2bf(b.y); t8[6] = f2bf(b.z); t8[7] = f2bf(b.w);
    *(uint4*)(Bs + c * 8) = *(uint4*)t8;
  }
  asm volatile("s_waitcnt vmcnt(0)" ::: "memory");
  __syncthreads();
  f32x4 acc[4][4];
  mfma_tile(As, Bs, acc);
  int w = tid >> 6, l = tid & 63;
  int wrb = (w >> 1) * 64, wcb = (w & 1) * 64, lo = l & 15, hi = l >> 4;
  float w2v[4], b1v[4];
  #pragma unroll
  for (int n = 0; n < 4; ++n){ int col = wcb + n * 16 + lo; w2v[n] = W2[col]; b1v[n] = b1[col]; }
  #pragma unroll
  for (int m = 0; m < 4; ++m){
    #pragma unroll
    for (int q = 0; q < 4; ++q){
      float p = 0.f;
      #pragma unroll
      for (int n = 0; n < 4; ++n){
        float hv = acc[m][n][q] + b1v[n];
        hv = hv >= 0.f ? hv : 0.2f * hv;   // leaky_relu(0.2)
        p += hv * w2v[n];
      }
      p += __shfl_xor(p, 1); p += __shfl_xor(p, 2);
      p += __shfl_xor(p, 4); p += __shfl_xor(p, 8);
      if (lo == 0) zpart[w & 1][wrb + m * 16 + hi * 4 + q] = p;
    }
  }
  __syncthreads();
  float Tloc = 0.f;
  if (tid < 128){
    float z = zpart[0][tid] + zpart[1][tid] + b2[0];
    float s = 1.f / (1.f + __expf(-z));
    float T = 0.95f * (1.f - s) + 0.05f;
    rTw[i0 + tid] = 1.f / T;
    Tloc = T;
  }
  float v = Tloc;
  #pragma unroll
  for (int o = 32; o; o >>= 1) v += __shfl_xor(v, o);
  if ((tid & 63) == 0) s4[tid >> 6] = v;
  __syncthreads();
  if (tid == 0) atomicAdd(out + OUT_AVG, (s4[0] + s4[1] + s4[2] + s4[3]) * (1.0f / 8192.0f));
}

// ------- phase 3: tot GEMM (A from L2) + exp row-reduce atomics + pos tile -------
__global__ __launch_bounds__(256, 4) void k_tot(const unsigned short* __restrict__ f1b,
    const unsigned short* __restrict__ f2b, const float* __restrict__ rTw,
    const float* __restrict__ posw, float* __restrict__ out){
  __shared__ __align__(16) unsigned short Bs[16384];   // 32 KB -> 4 blocks/CU
  __shared__ float rowacc[2][128];
  __shared__ float posS[128];
  __shared__ float rS[128];
  // bijective XCD-chunked swizzle (grid 4096 % 8 == 0)
  int bx = (blockIdx.x & 7) * 512 + (blockIdx.x >> 3);
  int rt = bx >> 6, ct = bx & 63;
  int tid = threadIdx.x, w = tid >> 6, l = tid & 63;
  int wr = (w >> 1) * 64, wc = (w & 1) * 64;
  int lo = l & 15, hi = l >> 4;
  stage_tile(f2b + (size_t)ct * 16384, Bs);
  if (tid < 128) posS[tid] = posw[ct * 128 + tid];
  else           rS[tid - 128] = rTw[rt * 128 + tid - 128];
  const unsigned short* Ag = f1b + (size_t)rt * 16384;
  f32x4 acc[4][4];
  f32x4 zero = {0.f, 0.f, 0.f, 0.f};
  #pragma unroll
  for (int m = 0; m < 4; ++m)
    #pragma unroll
    for (int n = 0; n < 4; ++n) acc[m][n] = zero;
  asm volatile("s_waitcnt vmcnt(0)" ::: "memory");
  __syncthreads();
  #pragma unroll
  for (int kk = 0; kk < 4; ++kk){
    bf16x8 af[4], bfv[4];
    #pragma unroll
    for (int m = 0; m < 4; ++m){
      int row = wr + m * 16 + lo;
      af[m] = *(const bf16x8*)(Ag + row * 128 + (kk * 4 + hi) * 8);   // L2 hit
    }
    #pragma unroll
    for (int n = 0; n < 4; ++n){
      int row = wc + n * 16 + lo;
      bfv[n] = *(const bf16x8*)(Bs + row * 128 + ((kk * 4 + hi) ^ (row & 7)) * 8);
    }
    #pragma unroll
    for (int m = 0; m < 4; ++m)
      #pragma unroll
      for (int n = 0; n < 4; ++n)
        acc[m][n] = __builtin_amdgcn_mfma_f32_16x16x32_bf16(af[m], bfv[n], acc[m][n], 0, 0, 0);
  }
  int wrb = wr;
  #pragma unroll
  for (int m = 0; m < 4; ++m){
    #pragma unroll
    for (int q = 0; q < 4; ++q){
      int lr = wrb + m * 16 + hi * 4 + q;
      float r = rS[lr];
      float p = __expf(acc[m][0][q] * r) + __expf(acc[m][1][q] * r)
              + __expf(acc[m][2][q] * r) + __expf(acc[m][3][q] * r);
      p += __shfl_xor(p, 1); p += __shfl_xor(p, 2);
      p += __shfl_xor(p, 4); p += __shfl_xor(p, 8);
      if (lo == 0) rowacc[w & 1][lr] = p;
    }
  }
  __syncthreads();
  if (tid < 128) atomicAdd(out + OUT_TOT + rt * 128 + tid, rowacc[0][tid] + rowacc[1][tid]);
  // pos_rating 128x128 tile, non-temporal streaming stores
  int c0 = (tid & 31) * 4;
  f32x4 p4 = *(const f32x4*)&posS[c0];
  #pragma unroll
  for (int pass = 0; pass < 16; ++pass){
    int row = pass * 8 + (tid >> 5);
    float r = rS[row];
    f32x4 e;
    e.x = __expf(p4.x * r); e.y = __expf(p4.y * r);
    e.z = __expf(p4.z * r); e.w = __expf(p4.w * r);
    __builtin_nontemporal_store(e, (f32x4*)(out + (size_t)(rt * 128 + row) * B_TOT + ct * 128 + c0));
  }
}

extern "C" void kernel_launch(void* const* d_in, const int* in_sizes, int n_in,
                              void* d_out, int out_size, void* d_ws, size_t ws_size,
                              hipStream_t stream){
  const float* x1 = (const float*)d_in[0];
  const float* x2 = (const float*)d_in[1];
  const int*   i1 = (const int*)d_in[2];
  const int*   i2 = (const int*)d_in[3];
  const float* W1 = (const float*)d_in[4];
  const float* b1 = (const float*)d_in[5];
  const float* W2 = (const float*)d_in[6];
  const float* b2 = (const float*)d_in[7];
  float* out = (float*)d_out;
  char* ws = (char*)d_ws;
  unsigned short* hb   = (unsigned short*)(ws);              // 2 MB
  unsigned short* f1b  = (unsigned short*)(ws + 2097152);    // 2 MB
  unsigned short* f2b  = (unsigned short*)(ws + 4194304);    // 2 MB
  float* posw  = (float*)(ws + 6291456);                     // 32 KB
  float* rTw   = (float*)(ws + 6324224);                     // 32 KB

  hipLaunchKernelGGL(k_feat,  dim3(8192), dim3(128), 0, stream, x1, x2, i1, i2, f1b, f2b, hb, posw, out);
  hipLaunchKernelGGL(k_lin,   dim3(64),   dim3(256), 0, stream, hb, W1, b1, W2, b2, rTw, out);
  hipLaunchKernelGGL(k_tot,   dim3(4096), dim3(256), 0, stream, f1b, f2b, rTw, posw, out);
}

// Round 6
// 91.098 us; speedup vs baseline: 1.3804x; 1.0467x over previous
//
#include <hip/hip_runtime.h>
#include <stdint.h>

typedef __bf16 bf16x8 __attribute__((ext_vector_type(8)));
typedef float f32x4 __attribute__((ext_vector_type(4)));
typedef __attribute__((address_space(3))) uint32_t as3u32;
typedef const __attribute__((address_space(1))) uint32_t as1u32;

#define B_TOT 8192
#define DD 128
#define OUT_TOT 67108864UL
#define OUT_AVG 67117056UL

__device__ inline unsigned short f2bf(float x){
  union { float f; uint32_t u; } v; v.f = x;
  return (unsigned short)((v.u + 0x7fffu + ((v.u >> 16) & 1u)) >> 16);
}

// ---------------- phase 1: gather + normalize + h + pos (+ zero accumulators) ----
__device__ inline float bsum128(float v, volatile float* s2){
  #pragma unroll
  for (int o = 32; o; o >>= 1) v += __shfl_xor(v, o);
  __syncthreads();
  if ((threadIdx.x & 63) == 0) s2[threadIdx.x >> 6] = v;
  __syncthreads();
  return s2[0] + s2[1];
}

__global__ __launch_bounds__(128) void k_feat(const float* __restrict__ x1,
    const float* __restrict__ x2, const int* __restrict__ i1a, const int* __restrict__ i2a,
    unsigned short* __restrict__ f1b, unsigned short* __restrict__ f2b,
    unsigned short* __restrict__ hb, float* __restrict__ posw, float* __restrict__ out){
  __shared__ float s2[2];
  int b = blockIdx.x, t = threadIdx.x;
  int gid = b * 128 + t;
  if (gid <= 8192) out[OUT_TOT + gid] = 0.f;   // zero tot_rating accum + avg slot
  size_t r1 = (size_t)i1a[b] * DD, r2 = (size_t)i2a[b] * DD;
  float v1 = x1[r1 + t], v2 = x2[r2 + t];
  float n1 = sqrtf(bsum128(v1 * v1, s2));
  float f1 = v1 / fmaxf(n1, 1e-12f);
  float n2 = sqrtf(bsum128(v2 * v2, s2));
  float f2 = v2 / fmaxf(n2, 1e-12f);
  float h = f1 * f2;
  float pos = bsum128(h, s2);
  int o = b * DD + t;
  f1b[o] = f2bf(f1); f2b[o] = f2bf(f2); hb[o] = f2bf(h);
  if (t == 0) posw[b] = pos;
}

// ---------------- shared staging (128x128 bf16 tile, XOR-swizzled) ----------------
// LDS chunk (row, cc) holds global chunk (row, cc ^ (row&7)); global_load_lds
// writes LDS linearly -> pre-swizzle the per-lane GLOBAL source (rule #21).
__device__ inline void stage_tile(const unsigned short* g, unsigned short* s){
  int tid = threadIdx.x;
  #pragma unroll
  for (int it = 0; it < 8; ++it){
    int c = tid + it * 256;          // 2048 chunks of 16B
    int row = c >> 4, cc = c & 15;
    int src = (row << 4) + (cc ^ (row & 7));
    __builtin_amdgcn_global_load_lds((as1u32*)(g + src * 8),
                                     (as3u32*)(s + c * 8), 16, 0, 0);
  }
}

// A-frag: row = lane&15, k = 8*(lane>>4)+e. C/D: col = lane&15, row=(lane>>4)*4+reg.
__device__ inline void mfma_tile(const unsigned short* As, const unsigned short* Bs,
                                 f32x4 acc[4][4]){
  int tid = threadIdx.x;
  int w = tid >> 6, l = tid & 63;
  int wr = (w >> 1) * 64, wc = (w & 1) * 64;
  int lo = l & 15, hi = l >> 4;
  f32x4 zero = {0.f, 0.f, 0.f, 0.f};
  #pragma unroll
  for (int m = 0; m < 4; ++m)
    #pragma unroll
    for (int n = 0; n < 4; ++n) acc[m][n] = zero;
  #pragma unroll
  for (int kk = 0; kk < 4; ++kk){
    bf16x8 af[4], bfv[4];
    #pragma unroll
    for (int m = 0; m < 4; ++m){
      int row = wr + m * 16 + lo;
      af[m] = *(const bf16x8*)(As + row * 128 + ((kk * 4 + hi) ^ (row & 7)) * 8);
    }
    #pragma unroll
    for (int n = 0; n < 4; ++n){
      int row = wc + n * 16 + lo;
      bfv[n] = *(const bf16x8*)(Bs + row * 128 + ((kk * 4 + hi) ^ (row & 7)) * 8);
    }
    #pragma unroll
    for (int m = 0; m < 4; ++m)
      #pragma unroll
      for (int n = 0; n < 4; ++n)
        acc[m][n] = __builtin_amdgcn_mfma_f32_16x16x32_bf16(af[m], bfv[n], acc[m][n], 0, 0, 0);
  }
}

// ---------------- phase 2: lin1 + leaky + lin2 + sigmoid -> rT, temp-mean -------
__global__ __launch_bounds__(256) void k_lin(const unsigned short* __restrict__ hb,
    const float* __restrict__ W1, const float* __restrict__ b1,
    const float* __restrict__ W2, const float* __restrict__ b2,
    float* __restrict__ rTw, float* __restrict__ out){
  __shared__ __align__(16) unsigned short As[16384];
  __shared__ __align__(16) unsigned short Bs[16384];
  __shared__ float zpart[2][128];
  __shared__ float s4[4];
  int i0 = blockIdx.x * 128;
  int tid = threadIdx.x;
  stage_tile(hb + (size_t)i0 * 128, As);
  #pragma unroll
  for (int it = 0; it < 8; ++it){
    int c = tid + it * 256;
    int row = c >> 4, cc = c & 15;
    int src = (row << 4) + (cc ^ (row & 7));
    const float4* g4 = (const float4*)(W1 + src * 8);
    float4 a = g4[0], b = g4[1];
    unsigned short t8[8];
    t8[0] = f2bf(a.x); t8[1] = f2bf(a.y); t8[2] = f2bf(a.z); t8[3] = f2bf(a.w);
    t8[4] = f2bf(b.x); t8[5] = f2bf(b.y); t8[6] = f2bf(b.z); t8[7] = f2bf(b.w);
    *(uint4*)(Bs + c * 8) = *(uint4*)t8;
  }
  asm volatile("s_waitcnt vmcnt(0)" ::: "memory");
  __syncthreads();
  f32x4 acc[4][4];
  mfma_tile(As, Bs, acc);
  int w = tid >> 6, l = tid & 63;
  int wrb = (w >> 1) * 64, wcb = (w & 1) * 64, lo = l & 15, hi = l >> 4;
  float w2v[4], b1v[4];
  #pragma unroll
  for (int n = 0; n < 4; ++n){ int col = wcb + n * 16 + lo; w2v[n] = W2[col]; b1v[n] = b1[col]; }
  #pragma unroll
  for (int m = 0; m < 4; ++m){
    #pragma unroll
    for (int q = 0; q < 4; ++q){
      float p = 0.f;
      #pragma unroll
      for (int n = 0; n < 4; ++n){
        float hv = acc[m][n][q] + b1v[n];
        hv = hv >= 0.f ? hv : 0.2f * hv;   // leaky_relu(0.2)
        p += hv * w2v[n];
      }
      p += __shfl_xor(p, 1); p += __shfl_xor(p, 2);
      p += __shfl_xor(p, 4); p += __shfl_xor(p, 8);
      if (lo == 0) zpart[w & 1][wrb + m * 16 + hi * 4 + q] = p;
    }
  }
  __syncthreads();
  float Tloc = 0.f;
  if (tid < 128){
    float z = zpart[0][tid] + zpart[1][tid] + b2[0];
    float s = 1.f / (1.f + __expf(-z));
    float T = 0.95f * (1.f - s) + 0.05f;
    rTw[i0 + tid] = 1.f / T;
    Tloc = T;
  }
  float v = Tloc;
  #pragma unroll
  for (int o = 32; o; o >>= 1) v += __shfl_xor(v, o);
  if ((tid & 63) == 0) s4[tid >> 6] = v;
  __syncthreads();
  if (tid == 0) atomicAdd(out + OUT_AVG, (s4[0] + s4[1] + s4[2] + s4[3]) * (1.0f / 8192.0f));
}

// ------- phase 3: persistent-tile tot GEMM + pos writer ------------------------
// Block = (rt, ctg): A tile staged once -> registers; loop 8 B-tiles through a
// single 32 KB LDS buffer; stores issue continuously (no end-of-block convoy).
__global__ __launch_bounds__(256, 2) void k_tot(const unsigned short* __restrict__ f1b,
    const unsigned short* __restrict__ f2b, const float* __restrict__ rTw,
    const float* __restrict__ posw, float* __restrict__ out){
  __shared__ __align__(16) unsigned short Buf[16384];   // 32 KB, A stage then B tiles
  __shared__ float rS[128];
  // XCD-chunked (grid 512 % 8 == 0): XCD k gets s in [64k,64k+64) -> fixed ctg=k
  // (its 8 B-tiles stay L2-hot), rt sweeps 0..63.
  int s = (blockIdx.x & 7) * 64 + (blockIdx.x >> 3);
  int rt = s & 63, ctg = s >> 6;
  int tid = threadIdx.x, w = tid >> 6, l = tid & 63;
  int wr = (w >> 1) * 64, wc = (w & 1) * 64;
  int lo = l & 15, hi = l >> 4;
  stage_tile(f1b + (size_t)rt * 16384, Buf);
  if (tid < 128) rS[tid] = rTw[rt * 128 + tid];
  asm volatile("s_waitcnt vmcnt(0)" ::: "memory");
  __syncthreads();
  bf16x8 af[4][4];                       // [kk][m] A fragments in registers
  #pragma unroll
  for (int kk = 0; kk < 4; ++kk)
    #pragma unroll
    for (int m = 0; m < 4; ++m){
      int row = wr + m * 16 + lo;
      af[kk][m] = *(const bf16x8*)(Buf + row * 128 + ((kk * 4 + hi) ^ (row & 7)) * 8);
    }
  asm volatile("s_waitcnt lgkmcnt(0)" ::: "memory");
  __syncthreads();                       // Buf free for B staging
  stage_tile(f2b + (size_t)(ctg * 8) * 16384, Buf);
  float pacc[4][4] = {{0.f,0.f,0.f,0.f},{0.f,0.f,0.f,0.f},{0.f,0.f,0.f,0.f},{0.f,0.f,0.f,0.f}};
  int prow = tid >> 5, pcol = (tid & 31) * 4;
  #pragma unroll 1
  for (int c8 = 0; c8 < 8; ++c8){
    int ct = ctg * 8 + c8;
    f32x4 p4 = *(const f32x4*)(posw + ct * 128 + pcol);   // issued pre-vmcnt(0)
    asm volatile("s_waitcnt vmcnt(0)" ::: "memory");
    __syncthreads();
    f32x4 acc[4][4];
    f32x4 zero = {0.f,0.f,0.f,0.f};
    #pragma unroll
    for (int m = 0; m < 4; ++m)
      #pragma unroll
      for (int n = 0; n < 4; ++n) acc[m][n] = zero;
    #pragma unroll
    for (int kk = 0; kk < 4; ++kk){
      bf16x8 bfv[4];
      #pragma unroll
      for (int n = 0; n < 4; ++n){
        int row = wc + n * 16 + lo;
        bfv[n] = *(const bf16x8*)(Buf + row * 128 + ((kk * 4 + hi) ^ (row & 7)) * 8);
      }
      #pragma unroll
      for (int m = 0; m < 4; ++m)
        #pragma unroll
        for (int n = 0; n < 4; ++n)
          acc[m][n] = __builtin_amdgcn_mfma_f32_16x16x32_bf16(af[kk][m], bfv[n], acc[m][n], 0, 0, 0);
    }
    asm volatile("s_waitcnt lgkmcnt(0)" ::: "memory");
    __syncthreads();                     // all waves done reading Buf
    if (c8 < 7) stage_tile(f2b + (size_t)(ct + 1) * 16384, Buf);  // prefetch next
    // epilogue runs while next-tile loads are in flight
    #pragma unroll
    for (int m = 0; m < 4; ++m)
      #pragma unroll
      for (int q = 0; q < 4; ++q){
        float r = rS[wr + m * 16 + hi * 4 + q];
        pacc[m][q] += __expf(acc[m][0][q] * r) + __expf(acc[m][1][q] * r)
                    + __expf(acc[m][2][q] * r) + __expf(acc[m][3][q] * r);
      }
    float* obase = out + (size_t)(rt * 128) * B_TOT + ct * 128 + pcol;
    #pragma unroll
    for (int pass = 0; pass < 16; ++pass){
      int row = pass * 8 + prow;
      float r = rS[row];
      f32x4 e;
      e.x = __expf(p4.x * r); e.y = __expf(p4.y * r);
      e.z = __expf(p4.z * r); e.w = __expf(p4.w * r);
      __builtin_nontemporal_store(e, (f32x4*)(obase + (size_t)row * B_TOT));
    }
  }
  // tot partials: reduce across the 16 col-lanes, one atomic set per block
  #pragma unroll
  for (int m = 0; m < 4; ++m)
    #pragma unroll
    for (int q = 0; q < 4; ++q){
      float p = pacc[m][q];
      p += __shfl_xor(p, 1); p += __shfl_xor(p, 2);
      p += __shfl_xor(p, 4); p += __shfl_xor(p, 8);
      if (lo == 0) atomicAdd(out + OUT_TOT + rt * 128 + wr + m * 16 + hi * 4 + q, p);
    }
}

extern "C" void kernel_launch(void* const* d_in, const int* in_sizes, int n_in,
                              void* d_out, int out_size, void* d_ws, size_t ws_size,
                              hipStream_t stream){
  const float* x1 = (const float*)d_in[0];
  const float* x2 = (const float*)d_in[1];
  const int*   i1 = (const int*)d_in[2];
  const int*   i2 = (const int*)d_in[3];
  const float* W1 = (const float*)d_in[4];
  const float* b1 = (const float*)d_in[5];
  const float* W2 = (const float*)d_in[6];
  const float* b2 = (const float*)d_in[7];
  float* out = (float*)d_out;
  char* ws = (char*)d_ws;
  unsigned short* hb   = (unsigned short*)(ws);              // 2 MB
  unsigned short* f1b  = (unsigned short*)(ws + 2097152);    // 2 MB
  unsigned short* f2b  = (unsigned short*)(ws + 4194304);    // 2 MB
  float* posw  = (float*)(ws + 6291456);                     // 32 KB
  float* rTw   = (float*)(ws + 6324224);                     // 32 KB

  hipLaunchKernelGGL(k_feat,  dim3(8192), dim3(128), 0, stream, x1, x2, i1, i2, f1b, f2b, hb, posw, out);
  hipLaunchKernelGGL(k_lin,   dim3(64),   dim3(256), 0, stream, hb, W1, b1, W2, b2, rTw, out);
  hipLaunchKernelGGL(k_tot,   dim3(512),  dim3(256), 0, stream, f1b, f2b, rTw, posw, out);
}